// Round 1
// baseline (336.081 us; speedup 1.0000x reference)
//
#include <hip/hip_runtime.h>

#define HW   65536   // 256*256
#define HW4  16384   // HW/4
#define NC   256     // 64*4
#define NB   64      // batch

// ---------------------------------------------------------------------------
// Kernel 1: per-(tensor,n,c) plane sums. blockIdx.x in [0,512): 0..255 = x
// planes, 256..511 = y planes. 256 threads, float4 loads, 4-way unrolled.
// ---------------------------------------------------------------------------
__global__ void __launch_bounds__(256)
plane_sum_kernel(const float* __restrict__ x, const float* __restrict__ y,
                 float* __restrict__ sums) {
    const int plane = blockIdx.x;                     // 0..511
    const float* src = (plane < NC) ? x : y;
    const int p = plane & (NC - 1);
    const float4* base = (const float4*)(src + (size_t)p * HW);

    float s = 0.f;
    // 16384 float4 / 256 threads = 64 each; unroll 4 for MLP (memory ILP)
    #pragma unroll
    for (int it = 0; it < 16; ++it) {
        int i = it * 1024 + threadIdx.x;
        float4 v0 = base[i];
        float4 v1 = base[i + 256];
        float4 v2 = base[i + 512];
        float4 v3 = base[i + 768];
        s += (v0.x + v0.y) + (v0.z + v0.w);
        s += (v1.x + v1.y) + (v1.z + v1.w);
        s += (v2.x + v2.y) + (v2.z + v2.w);
        s += (v3.x + v3.y) + (v3.z + v3.w);
    }
    // wave-64 shuffle reduce
    #pragma unroll
    for (int off = 32; off > 0; off >>= 1)
        s += __shfl_down(s, off);
    __shared__ float ls[4];
    const int lane = threadIdx.x & 63, wv = threadIdx.x >> 6;
    if (lane == 0) ls[wv] = s;
    __syncthreads();
    if (threadIdx.x == 0)
        sums[plane] = (ls[0] + ls[1]) + (ls[2] + ls[3]);
}

// ---------------------------------------------------------------------------
// Kernel 2: gates. 1 block, 64 threads (one per sample). mean -> 4->2 -> 2->2
// affine -> threshold at 0. masks[n*4 + {0,1,2,3}] = {mx0, mx1, my0, my1}.
// ---------------------------------------------------------------------------
__global__ void gates_kernel(const float* __restrict__ sums,
                             const float* __restrict__ w1, const float* __restrict__ b1,
                             const float* __restrict__ w2, const float* __restrict__ b2,
                             float* __restrict__ masks) {
    const int n = threadIdx.x;
    if (n >= NB) return;
    const float inv = 1.0f / (float)HW;
    float g[2][2];
    #pragma unroll
    for (int t = 0; t < 2; ++t) {
        const float* sp = sums + t * NC + n * 4;
        float p0 = sp[0] * inv, p1 = sp[1] * inv, p2 = sp[2] * inv, p3 = sp[3] * inv;
        float h0 = w1[0] * p0 + w1[1] * p1 + w1[2] * p2 + w1[3] * p3 + b1[0];
        float h1 = w1[4] * p0 + w1[5] * p1 + w1[6] * p2 + w1[7] * p3 + b1[1];
        g[t][0] = w2[0] * h0 + w2[1] * h1 + b2[0];
        g[t][1] = w2[2] * h0 + w2[3] * h1 + b2[1];
    }
    masks[n * 4 + 0] = g[0][0] > 0.f ? 1.f : 0.f;  // mx0
    masks[n * 4 + 1] = g[0][1] > 0.f ? 1.f : 0.f;  // mx1
    masks[n * 4 + 2] = g[1][0] > 0.f ? 1.f : 0.f;  // my0
    masks[n * 4 + 3] = g[1][1] > 0.f ? 1.f : 0.f;  // my1
}

// ---------------------------------------------------------------------------
// Kernel 3: fused masked 1x1 convs. blockIdx.x = n*64 + chunk; thread handles
// one float4 spatial position. Masks & weights are wave-uniform (scalar regs);
// m*W folded on SALU, exact since m in {0.0, 1.0}.
// ---------------------------------------------------------------------------
__global__ void __launch_bounds__(256)
main_kernel(const float* __restrict__ x, const float* __restrict__ y,
            const float* __restrict__ masks,
            const float* __restrict__ we1, const float* __restrict__ be1,
            const float* __restrict__ we2, const float* __restrict__ be2,
            const float* __restrict__ we3, const float* __restrict__ be3,
            const float* __restrict__ we4, const float* __restrict__ be4,
            float* __restrict__ outx, float* __restrict__ outy) {
    const int blk   = blockIdx.x;
    const int n     = blk >> 6;
    const int chunk = blk & 63;
    const int hw4   = chunk * 256 + threadIdx.x;      // float4 index in plane

    const float mx0 = masks[n * 4 + 0];
    const float mx1 = masks[n * 4 + 1];
    const float my0 = masks[n * 4 + 2];
    const float my1 = masks[n * 4 + 3];

    const float4* xb = (const float4*)(x + (size_t)n * 4 * HW);
    const float4* yb = (const float4*)(y + (size_t)n * 4 * HW);

    float4 xv[4], yv[4];
    #pragma unroll
    for (int c = 0; c < 4; ++c) {
        xv[c] = xb[c * HW4 + hw4];
        yv[c] = yb[c * HW4 + hw4];
    }

    // out_x: 4 channels = mx0*conv(x, we1) + my0*conv(y, we3)
    float4* ox = (float4*)(outx + (size_t)n * 4 * HW);
    #pragma unroll
    for (int o = 0; o < 4; ++o) {
        const float bb = mx0 * be1[o] + my0 * be3[o];
        float4 a = {bb, bb, bb, bb};
        #pragma unroll
        for (int c = 0; c < 4; ++c) {
            const float wx = mx0 * we1[o * 4 + c];
            const float wy = my0 * we3[o * 4 + c];
            a.x += wx * xv[c].x + wy * yv[c].x;
            a.y += wx * xv[c].y + wy * yv[c].y;
            a.z += wx * xv[c].z + wy * yv[c].z;
            a.w += wx * xv[c].w + wy * yv[c].w;
        }
        ox[o * HW4 + hw4] = a;
    }

    // out_y: 8 channels = mx1*conv(x, we2) + my1*conv(y, we4)
    float4* oy = (float4*)(outy + (size_t)n * 8 * HW);
    #pragma unroll
    for (int o = 0; o < 8; ++o) {
        const float bb = mx1 * be2[o] + my1 * be4[o];
        float4 a = {bb, bb, bb, bb};
        #pragma unroll
        for (int c = 0; c < 4; ++c) {
            const float wx = mx1 * we2[o * 4 + c];
            const float wy = my1 * we4[o * 4 + c];
            a.x += wx * xv[c].x + wy * yv[c].x;
            a.y += wx * xv[c].y + wy * yv[c].y;
            a.z += wx * xv[c].z + wy * yv[c].z;
            a.w += wx * xv[c].w + wy * yv[c].w;
        }
        oy[o * HW4 + hw4] = a;
    }
}

extern "C" void kernel_launch(void* const* d_in, const int* in_sizes, int n_in,
                              void* d_out, int out_size, void* d_ws, size_t ws_size,
                              hipStream_t stream) {
    const float* x     = (const float*)d_in[0];
    const float* y     = (const float*)d_in[1];
    const float* w_rf1 = (const float*)d_in[2];
    const float* b_rf1 = (const float*)d_in[3];
    const float* w_rf2 = (const float*)d_in[4];
    const float* b_rf2 = (const float*)d_in[5];
    const float* w_e1  = (const float*)d_in[6];
    const float* b_e1  = (const float*)d_in[7];
    const float* w_e2  = (const float*)d_in[8];
    const float* b_e2  = (const float*)d_in[9];
    const float* w_e3  = (const float*)d_in[10];
    const float* b_e3  = (const float*)d_in[11];
    const float* w_e4  = (const float*)d_in[12];
    const float* b_e4  = (const float*)d_in[13];

    float* ws    = (float*)d_ws;
    float* sums  = ws;          // 512 floats
    float* masks = ws + 512;    // 256 floats

    float* outx = (float*)d_out;                          // [64,4,256,256]
    float* outy = outx + (size_t)NB * 4 * HW;             // [64,8,256,256]

    hipLaunchKernelGGL(plane_sum_kernel, dim3(512), dim3(256), 0, stream,
                       x, y, sums);
    hipLaunchKernelGGL(gates_kernel, dim3(1), dim3(64), 0, stream,
                       sums, w_rf1, b_rf1, w_rf2, b_rf2, masks);
    hipLaunchKernelGGL(main_kernel, dim3(4096), dim3(256), 0, stream,
                       x, y, masks,
                       w_e1, b_e1, w_e2, b_e2, w_e3, b_e3, w_e4, b_e4,
                       outx, outy);
}

// Round 3
// 333.525 us; speedup vs baseline: 1.0077x; 1.0077x over previous
//
#include <hip/hip_runtime.h>

#define HW   65536   // 256*256
#define HW4  16384   // HW/4
#define NC   256     // 64*4 planes per tensor
#define NB   64      // batch

typedef float vf4 __attribute__((ext_vector_type(4)));  // native vector for nt-store

// ---------------------------------------------------------------------------
// Kernel 1: partial plane sums. 2048 blocks = 512 planes x 4 quarters.
// Plane 0..255 = x, 256..511 = y. Each block sums 4096 float4 (1/4 plane).
// 8 blocks/CU -> 32 waves/CU for latency hiding (vs 8 in R1).
// ---------------------------------------------------------------------------
__global__ void __launch_bounds__(256)
partial_sum_kernel(const float* __restrict__ x, const float* __restrict__ y,
                   float* __restrict__ partials) {
    const int blk   = blockIdx.x;           // 0..2047
    const int plane = blk >> 2;             // 0..511
    const int q     = blk & 3;              // quarter
    const float* src = (plane < NC) ? x : y;
    const int p = plane & (NC - 1);
    const vf4* base = (const vf4*)(src + (size_t)p * HW) + q * 4096;

    float s = 0.f;
    #pragma unroll
    for (int it = 0; it < 4; ++it) {
        int i = it * 1024 + threadIdx.x;
        vf4 v0 = base[i];
        vf4 v1 = base[i + 256];
        vf4 v2 = base[i + 512];
        vf4 v3 = base[i + 768];
        s += (v0.x + v0.y) + (v0.z + v0.w);
        s += (v1.x + v1.y) + (v1.z + v1.w);
        s += (v2.x + v2.y) + (v2.z + v2.w);
        s += (v3.x + v3.y) + (v3.z + v3.w);
    }
    #pragma unroll
    for (int off = 32; off > 0; off >>= 1)
        s += __shfl_down(s, off);
    __shared__ float ls[4];
    const int lane = threadIdx.x & 63, wv = threadIdx.x >> 6;
    if (lane == 0) ls[wv] = s;
    __syncthreads();
    if (threadIdx.x == 0)
        partials[blk] = (ls[0] + ls[1]) + (ls[2] + ls[3]);
}

// ---------------------------------------------------------------------------
// Kernel 2: gates. 1 block, 64 threads (one per sample). Reduces 4 partials
// per plane, then mean -> 4->2 -> 2->2 affine -> threshold at 0.
// masks[n*4 + {0,1,2,3}] = {mx0, mx1, my0, my1}.
// ---------------------------------------------------------------------------
__global__ void gates_kernel(const float* __restrict__ partials,
                             const float* __restrict__ w1, const float* __restrict__ b1,
                             const float* __restrict__ w2, const float* __restrict__ b2,
                             float* __restrict__ masks) {
    const int n = threadIdx.x;
    if (n >= NB) return;
    const float inv = 1.0f / (float)HW;
    float g[2][2];
    #pragma unroll
    for (int t = 0; t < 2; ++t) {
        float p[4];
        #pragma unroll
        for (int c = 0; c < 4; ++c) {
            const int plane = t * NC + n * 4 + c;
            const float* pp = partials + plane * 4;
            p[c] = ((pp[0] + pp[1]) + (pp[2] + pp[3])) * inv;
        }
        float h0 = w1[0]*p[0] + w1[1]*p[1] + w1[2]*p[2] + w1[3]*p[3] + b1[0];
        float h1 = w1[4]*p[0] + w1[5]*p[1] + w1[6]*p[2] + w1[7]*p[3] + b1[1];
        g[t][0] = w2[0]*h0 + w2[1]*h1 + b2[0];
        g[t][1] = w2[2]*h0 + w2[3]*h1 + b2[1];
    }
    masks[n * 4 + 0] = g[0][0] > 0.f ? 1.f : 0.f;  // mx0
    masks[n * 4 + 1] = g[0][1] > 0.f ? 1.f : 0.f;  // mx1
    masks[n * 4 + 2] = g[1][0] > 0.f ? 1.f : 0.f;  // my0
    masks[n * 4 + 3] = g[1][1] > 0.f ? 1.f : 0.f;  // my1
}

// ---------------------------------------------------------------------------
// Kernel 3: fused masked 1x1 convs. blockIdx.x = n*64 + chunk; thread handles
// one float4 spatial position. Masks & weights are wave-uniform (scalar regs);
// m*W folded on SALU, exact since m in {0.0, 1.0}. Nontemporal stores keep
// x,y resident in Infinity Cache (134 MB < 256 MB) for this kernel's reads.
// ---------------------------------------------------------------------------
__global__ void __launch_bounds__(256)
main_kernel(const float* __restrict__ x, const float* __restrict__ y,
            const float* __restrict__ masks,
            const float* __restrict__ we1, const float* __restrict__ be1,
            const float* __restrict__ we2, const float* __restrict__ be2,
            const float* __restrict__ we3, const float* __restrict__ be3,
            const float* __restrict__ we4, const float* __restrict__ be4,
            float* __restrict__ outx, float* __restrict__ outy) {
    const int blk   = blockIdx.x;
    const int n     = blk >> 6;
    const int chunk = blk & 63;
    const int hw4   = chunk * 256 + threadIdx.x;      // float4 index in plane

    const float mx0 = masks[n * 4 + 0];
    const float mx1 = masks[n * 4 + 1];
    const float my0 = masks[n * 4 + 2];
    const float my1 = masks[n * 4 + 3];

    const vf4* xb = (const vf4*)(x + (size_t)n * 4 * HW);
    const vf4* yb = (const vf4*)(y + (size_t)n * 4 * HW);

    vf4 xv[4], yv[4];
    #pragma unroll
    for (int c = 0; c < 4; ++c) {
        xv[c] = xb[c * HW4 + hw4];
        yv[c] = yb[c * HW4 + hw4];
    }

    // out_x: 4 channels = mx0*conv(x, we1) + my0*conv(y, we3)
    vf4* ox = (vf4*)(outx + (size_t)n * 4 * HW);
    #pragma unroll
    for (int o = 0; o < 4; ++o) {
        const float bb = mx0 * be1[o] + my0 * be3[o];
        vf4 a = {bb, bb, bb, bb};
        #pragma unroll
        for (int c = 0; c < 4; ++c) {
            const float wx = mx0 * we1[o * 4 + c];
            const float wy = my0 * we3[o * 4 + c];
            a += wx * xv[c] + wy * yv[c];
        }
        __builtin_nontemporal_store(a, &ox[o * HW4 + hw4]);
    }

    // out_y: 8 channels = mx1*conv(x, we2) + my1*conv(y, we4)
    vf4* oy = (vf4*)(outy + (size_t)n * 8 * HW);
    #pragma unroll
    for (int o = 0; o < 8; ++o) {
        const float bb = mx1 * be2[o] + my1 * be4[o];
        vf4 a = {bb, bb, bb, bb};
        #pragma unroll
        for (int c = 0; c < 4; ++c) {
            const float wx = mx1 * we2[o * 4 + c];
            const float wy = my1 * we4[o * 4 + c];
            a += wx * xv[c] + wy * yv[c];
        }
        __builtin_nontemporal_store(a, &oy[o * HW4 + hw4]);
    }
}

extern "C" void kernel_launch(void* const* d_in, const int* in_sizes, int n_in,
                              void* d_out, int out_size, void* d_ws, size_t ws_size,
                              hipStream_t stream) {
    const float* x     = (const float*)d_in[0];
    const float* y     = (const float*)d_in[1];
    const float* w_rf1 = (const float*)d_in[2];
    const float* b_rf1 = (const float*)d_in[3];
    const float* w_rf2 = (const float*)d_in[4];
    const float* b_rf2 = (const float*)d_in[5];
    const float* w_e1  = (const float*)d_in[6];
    const float* b_e1  = (const float*)d_in[7];
    const float* w_e2  = (const float*)d_in[8];
    const float* b_e2  = (const float*)d_in[9];
    const float* w_e3  = (const float*)d_in[10];
    const float* b_e3  = (const float*)d_in[11];
    const float* w_e4  = (const float*)d_in[12];
    const float* b_e4  = (const float*)d_in[13];

    float* ws       = (float*)d_ws;
    float* partials = ws;           // 2048 floats
    float* masks    = ws + 2048;    // 256 floats

    float* outx = (float*)d_out;                          // [64,4,256,256]
    float* outy = outx + (size_t)NB * 4 * HW;             // [64,8,256,256]

    hipLaunchKernelGGL(partial_sum_kernel, dim3(2048), dim3(256), 0, stream,
                       x, y, partials);
    hipLaunchKernelGGL(gates_kernel, dim3(1), dim3(64), 0, stream,
                       partials, w_rf1, b_rf1, w_rf2, b_rf2, masks);
    hipLaunchKernelGGL(main_kernel, dim3(4096), dim3(256), 0, stream,
                       x, y, masks,
                       w_e1, b_e1, w_e2, b_e2, w_e3, b_e3, w_e4, b_e4,
                       outx, outy);
}